// Round 1
// 268.799 us; speedup vs baseline: 1.0137x; 1.0137x over previous
//
#include <hip/hip_runtime.h>

// DiffTreeInterpreter: row-pair CSR gather, pipelined 4-pairs-per-wave edition.
//
// Output row r (batch b):
//   half: r<2048: car from role 2r (scale op0*w0), cdr from role 2r+1>=3 (op1*w1)
//   cons: all r: from role r>>1 (scale op2*w2 if r even else op2*w3)
//   root: out[b,1,:] += op2*root_filler[b]
//
// gather: one wave owns FOUR row-pairs: two "lower" pairs (q = 2i, 2i+1 < 1024,
// which have half contributions) and two "upper" pairs (q+1024, cons-only).
// All structure loads (6 static wave-wide loads) are issued first, then ALL
// mem-row loads for all four pairs, then four accumulate+store phases. This
// exposes the round-1 (structure) latency once per 4 pairs and keeps ~20-40
// row loads in flight per wave instead of ~12 with a serial round-trip each.

namespace {
constexpr int kB = 32;
constexpr int kL = 128;
constexpr int kF = 128;
constexpr int kR = 4096;
constexpr int kN = 262144;
constexpr int kQ = 2048;       // row-pairs per batch == half-rows per batch
constexpr int kNP = kB * kQ;   // 65536 keys
constexpr int kCap = 16;       // entries per record; P(Poisson(4)>16)~4e-7
constexpr int kOvfMax = 65536;

// workspace layout (bytes)
constexpr size_t kOffRowCnt  = 0;        // kNP*4  = 262144
constexpr size_t kOffConsCnt = 262144;   // kNP*4  = 262144
constexpr size_t kOffOvfCnt  = 524288;   // 4 (pad 16)
constexpr size_t kOffOvf     = 524304;   // kOvfMax*16 = 1048576
constexpr size_t kOffRowEnt  = 1572880;  // kNP*kCap*8  = 8388608  (int2)
constexpr size_t kOffConsEnt = 9961488;  // kNP*kCap*16 = 16777216 (int4)
// end: 26,738,704 bytes (~25.5 MB)
}  // namespace

__global__ __launch_bounds__(256) void build_kernel(
    const float4* __restrict__ aw, const float* __restrict__ opd,
    const int* __restrict__ bidx, const int* __restrict__ sidx,
    const int* __restrict__ ridx,
    int* __restrict__ rowcnt, int* __restrict__ conscnt,
    int* __restrict__ ovf_cnt, int4* __restrict__ ovf,
    int2* __restrict__ rowent, int4* __restrict__ consent) {
  int n = blockIdx.x * 256 + threadIdx.x;
  if (n >= kN) return;
  int b = bidx[n];
  int s = sidx[n];
  int rr = ridx[n];
  float4 w = aw[b * kL + s];
  float op0 = opd[3 * b + 0];
  float op1 = opd[3 * b + 1];
  float op2 = opd[3 * b + 2];

  // half contribution -> row rr>>1 (car if even, cdr if odd>=3; role 1 dropped)
  bool even = (rr & 1) == 0;
  if (even || rr >= 3) {
    float sc = even ? op0 * w.x : op1 * w.y;
    int key = (b << 11) | (rr >> 1);
    int pos = atomicAdd(&rowcnt[key], 1);
    if (pos < kCap) {
      rowent[key * kCap + pos] = make_int2(n, __float_as_int(sc));
    } else {
      int o = atomicAdd(ovf_cnt, 1);
      if (o < kOvfMax)
        ovf[o] = make_int4(b * kR + (rr >> 1), n, __float_as_int(sc), 0);
    }
  }
  // cons contribution -> rows 2rr, 2rr+1 : ONE entry (n, s1, s2)
  if (rr < kQ) {
    int key = (b << 11) | rr;
    int pos = atomicAdd(&conscnt[key], 1);
    if (pos < kCap) {
      consent[key * kCap + pos] =
          make_int4(n, __float_as_int(op2 * w.z), __float_as_int(op2 * w.w), 0);
    } else {
      int o = atomicAdd(ovf_cnt, 2);
      if (o < kOvfMax)
        ovf[o] = make_int4(b * kR + 2 * rr, n, __float_as_int(op2 * w.z), 0);
      if (o + 1 < kOvfMax)
        ovf[o + 1] =
            make_int4(b * kR + 2 * rr + 1, n, __float_as_int(op2 * w.w), 0);
    }
  }
}

// ---- gather macros --------------------------------------------------------
// cons record for one pair lives in 32 int2 lanes of CE starting at BASE:
//   lane BASE+2j   = (n, s1)   lane BASE+2j+1 = (s2, pad)
#define CONS_ISSUE(M, CE, BASE, CNT)                     \
  _Pragma("unroll") for (int j = 0; j < 4; ++j) {        \
    int nn = __shfl((CE).x, (BASE) + 2 * j);             \
    nn = (j < (CNT)) ? nn : 0;                           \
    M[j] = mem2[(size_t)nn * 64 + t];                    \
  }

// half record (16 entries) lives in 16 lanes of HE starting at BASE:
//   lane BASE+j = (n, scale)
#define HALF_ISSUE(M, HE, BASE, CNT)                     \
  if ((CNT) > 0) {                                       \
    _Pragma("unroll") for (int j = 0; j < 4; ++j) {      \
      int nn = __shfl((HE).x, (BASE) + j);               \
      nn = (j < (CNT)) ? nn : 0;                         \
      M[j] = mem2[(size_t)nn * 64 + t];                  \
    }                                                    \
    if ((CNT) > 4) {                                     \
      _Pragma("unroll") for (int j = 4; j < 8; ++j) {    \
        int nn = __shfl((HE).x, (BASE) + j);             \
        nn = (j < (CNT)) ? nn : 0;                       \
        M[j] = mem2[(size_t)nn * 64 + t];                \
      }                                                  \
    }                                                    \
  }

#define CONS_ACC(M, CE, BASE, CNT)                                     \
  _Pragma("unroll") for (int j = 0; j < 4; ++j) {                      \
    bool v = j < (CNT);                                                \
    float a = __int_as_float(__shfl((CE).y, (BASE) + 2 * j));          \
    float bb = __int_as_float(__shfl((CE).x, (BASE) + 2 * j + 1));     \
    a = v ? a : 0.f;                                                   \
    bb = v ? bb : 0.f;                                                 \
    ax0 += a * M[j].x;                                                 \
    ay0 += a * M[j].y;                                                 \
    ax1 += bb * M[j].x;                                                \
    ay1 += bb * M[j].y;                                                \
  }                                                                    \
  for (int ii = 4; ii < (CNT); ii += 4) { /* rare: P(Poisson(2)>4) */  \
    _Pragma("unroll") for (int j = 0; j < 4; ++j) {                    \
      int idx = ii + j;                                                \
      bool v = idx < (CNT);                                            \
      int nn = __shfl((CE).x, (BASE) + 2 * idx);                       \
      float a = __int_as_float(__shfl((CE).y, (BASE) + 2 * idx));      \
      float bb = __int_as_float(__shfl((CE).x, (BASE) + 2 * idx + 1)); \
      nn = v ? nn : 0;                                                 \
      a = v ? a : 0.f;                                                 \
      bb = v ? bb : 0.f;                                               \
      float2 m = mem2[(size_t)nn * 64 + t];                            \
      ax0 += a * m.x;                                                  \
      ay0 += a * m.y;                                                  \
      ax1 += bb * m.x;                                                 \
      ay1 += bb * m.y;                                                 \
    }                                                                  \
  }

#define HALF_ACC(M, HE, BASE, CNT, AX, AY)                             \
  _Pragma("unroll") for (int j = 0; j < 8; ++j) {                      \
    bool v = j < (CNT);                                                \
    float s = __int_as_float(__shfl((HE).y, (BASE) + j));              \
    s = v ? s : 0.f;                                                   \
    AX += s * M[j].x;                                                  \
    AY += s * M[j].y;                                                  \
  }                                                                    \
  for (int ii = 8; ii < (CNT); ii += 4) { /* rare: P(Poisson(4)>8) */  \
    _Pragma("unroll") for (int j = 0; j < 4; ++j) {                    \
      int idx = ii + j;                                                \
      bool v = idx < (CNT);                                            \
      int nn = __shfl((HE).x, (BASE) + idx);                           \
      float s = __int_as_float(__shfl((HE).y, (BASE) + idx));          \
      nn = v ? nn : 0;                                                 \
      s = v ? s : 0.f;                                                 \
      float2 m = mem2[(size_t)nn * 64 + t];                            \
      AX += s * m.x;                                                   \
      AY += s * m.y;                                                   \
    }                                                                  \
  }

__global__ __launch_bounds__(256) void gather_kernel(
    const float2* __restrict__ mem2, const float2* __restrict__ root2,
    const float* __restrict__ opd,
    const int* __restrict__ rowcnt, const int* __restrict__ conscnt,
    const int2* __restrict__ rowent2, const int2* __restrict__ consent2,
    float2* __restrict__ out2) {
  const int wv = blockIdx.x * 4 + (threadIdx.x >> 6);  // wave id, 16384 total
  const int t = threadIdx.x & 63;                      // lane: features 2t,2t+1
  const int b = wv >> 9;        // 512 waves per batch
  const int i = wv & 511;
  const int plo = (b << 11) | (2 * i);  // pairs plo, plo+1 : q<1024, have halves
  const int phi = plo + 1024;           // pairs phi, phi+1 : cons only
  const int kb4 = (b << 11) | (4 * i);  // first of 4 consecutive half-row keys

  // ---- structure: 6 static coalesced loads cover all 4 pairs ----
  const int2 cnlo = *(const int2*)(conscnt + plo);
  const int2 cnhi = *(const int2*)(conscnt + phi);
  const int4 hc4 = *(const int4*)(rowcnt + kb4);
  const int2 ceL = consent2[(size_t)plo * 32 + t];  // lanes 0-31 pair plo, 32-63 pair plo+1
  const int2 ceH = consent2[(size_t)phi * 32 + t];
  const int2 he = rowent2[(size_t)kb4 * 16 + t];    // 4 half-records, 16 lanes each

  const int cn0 = min(__builtin_amdgcn_readfirstlane(cnlo.x), kCap);
  const int cn1 = min(__builtin_amdgcn_readfirstlane(cnlo.y), kCap);
  const int cn2 = min(__builtin_amdgcn_readfirstlane(cnhi.x), kCap);
  const int cn3 = min(__builtin_amdgcn_readfirstlane(cnhi.y), kCap);
  const int h00 = min(__builtin_amdgcn_readfirstlane(hc4.x), kCap);  // row 4i
  const int h01 = min(__builtin_amdgcn_readfirstlane(hc4.y), kCap);  // row 4i+1
  const int h10 = min(__builtin_amdgcn_readfirstlane(hc4.z), kCap);  // row 4i+2
  const int h11 = min(__builtin_amdgcn_readfirstlane(hc4.w), kCap);  // row 4i+3

  // ---- row buffers (static indexing only; init so 0-masked FMAs see finite)
  float2 mcA[4], mcB[4], mcC[4], mcD[4];
  float2 m0A[8], m1A[8], m0B[8], m1B[8];
#pragma unroll
  for (int j = 0; j < 8; ++j) {
    m0A[j] = make_float2(0.f, 0.f);
    m1A[j] = make_float2(0.f, 0.f);
    m0B[j] = make_float2(0.f, 0.f);
    m1B[j] = make_float2(0.f, 0.f);
  }

  // ---- issue ALL mem-row loads for all 4 pairs ----
  CONS_ISSUE(mcA, ceL, 0, cn0);
  CONS_ISSUE(mcB, ceL, 32, cn1);
  CONS_ISSUE(mcC, ceH, 0, cn2);
  CONS_ISSUE(mcD, ceH, 32, cn3);
  HALF_ISSUE(m0A, he, 0, h00);
  HALF_ISSUE(m1A, he, 16, h01);
  HALF_ISSUE(m0B, he, 32, h10);
  HALF_ISSUE(m1B, he, 48, h11);

  // ---- accumulate + store, pair by pair ----
  {  // pair plo (rows 4i, 4i+1)
    float ax0 = 0.f, ay0 = 0.f, ax1 = 0.f, ay1 = 0.f;
    CONS_ACC(mcA, ceL, 0, cn0);
    HALF_ACC(m0A, he, 0, h00, ax0, ay0);
    HALF_ACC(m1A, he, 16, h01, ax1, ay1);
    if ((plo & (kQ - 1)) == 0) {  // q==0 -> out row 1 gets op2*root_filler
      float op2 = opd[3 * b + 2];
      float2 rf = root2[b * 64 + t];
      ax1 += op2 * rf.x;
      ay1 += op2 * rf.y;
    }
    size_t orow = (size_t)plo * 128 + t;
    out2[orow] = make_float2(ax0, ay0);
    out2[orow + 64] = make_float2(ax1, ay1);
  }
  {  // pair plo+1 (rows 4i+2, 4i+3)
    float ax0 = 0.f, ay0 = 0.f, ax1 = 0.f, ay1 = 0.f;
    CONS_ACC(mcB, ceL, 32, cn1);
    HALF_ACC(m0B, he, 32, h10, ax0, ay0);
    HALF_ACC(m1B, he, 48, h11, ax1, ay1);
    size_t orow = (size_t)(plo + 1) * 128 + t;
    out2[orow] = make_float2(ax0, ay0);
    out2[orow + 64] = make_float2(ax1, ay1);
  }
  {  // pair phi (cons only)
    float ax0 = 0.f, ay0 = 0.f, ax1 = 0.f, ay1 = 0.f;
    CONS_ACC(mcC, ceH, 0, cn2);
    size_t orow = (size_t)phi * 128 + t;
    out2[orow] = make_float2(ax0, ay0);
    out2[orow + 64] = make_float2(ax1, ay1);
  }
  {  // pair phi+1 (cons only)
    float ax0 = 0.f, ay0 = 0.f, ax1 = 0.f, ay1 = 0.f;
    CONS_ACC(mcD, ceH, 32, cn3);
    size_t orow = (size_t)(phi + 1) * 128 + t;
    out2[orow] = make_float2(ax0, ay0);
    out2[orow + 64] = make_float2(ax1, ay1);
  }
}

// Overflow fallback (expected ~0 entries): direct atomic add.
// Must run AFTER gather_kernel (gather writes out with '=').
__global__ __launch_bounds__(128) void ovf_kernel(
    const float* __restrict__ mem, const int* __restrict__ ovf_cnt,
    const int4* __restrict__ ovf, float* __restrict__ out) {
  int m = *ovf_cnt;
  if (m > kOvfMax) m = kOvfMax;
  const int t = threadIdx.x;  // feature 0..127
  for (int i = blockIdx.x; i < m; i += gridDim.x) {
    int4 e = ovf[i];
    float sc = __int_as_float(e.z);
    atomicAdd(&out[(size_t)e.x * kF + t], sc * mem[(size_t)e.y * kF + t]);
  }
}

extern "C" void kernel_launch(void* const* d_in, const int* in_sizes, int n_in,
                              void* d_out, int out_size, void* d_ws, size_t ws_size,
                              hipStream_t stream) {
  const float* mem   = (const float*)d_in[0];   // (N, F)
  const float* aw    = (const float*)d_in[1];   // (B, L, 4)
  const float* rootf = (const float*)d_in[2];   // (B, F)
  const float* opd   = (const float*)d_in[3];   // (B, 3)
  const int* bidx    = (const int*)d_in[4];     // (N,)
  const int* sidx    = (const int*)d_in[5];     // (N,)
  const int* ridx    = (const int*)d_in[6];     // (N,)

  char* ws = (char*)d_ws;
  int* rowcnt   = (int*)(ws + kOffRowCnt);
  int* conscnt  = (int*)(ws + kOffConsCnt);
  int* ovf_cnt  = (int*)(ws + kOffOvfCnt);
  int4* ovf     = (int4*)(ws + kOffOvf);
  int2* rowent  = (int2*)(ws + kOffRowEnt);
  int4* consent = (int4*)(ws + kOffConsEnt);

  // zero all counters in one contiguous memset (ws is poisoned 0xAA each call)
  hipMemsetAsync(ws, 0, kOffOvfCnt + 16, stream);

  build_kernel<<<kN / 256, 256, 0, stream>>>(
      (const float4*)aw, opd, bidx, sidx, ridx, rowcnt, conscnt, ovf_cnt, ovf,
      rowent, consent);

  // 16 pairs per 256-thread block (4 waves x 4 pairs) -> 4096 blocks
  gather_kernel<<<kNP / 16, 256, 0, stream>>>(
      (const float2*)mem, (const float2*)rootf, opd, rowcnt, conscnt,
      (const int2*)rowent, (const int2*)consent, (float2*)d_out);

  ovf_kernel<<<64, 128, 0, stream>>>(mem, ovf_cnt, ovf, (float*)d_out);
}